// Round 4
// baseline (271.060 us; speedup 1.0000x reference)
//
#include <hip/hip_runtime.h>

// LocalizationLoss: B=1048576, N=3, C=7. output (B,3,7) fp32, target (B,3,5) fp32.
// result = (5*(Sx+Sy+2*Swh) + 3*Sce - 0.5*Sbce)/(B*N) + 0.5   (scalar fp32)
//
// History: R1 59us partials. R2 wave-private LDS 62us. R5 32-row shots 58us.
// R6 gl_lds 4-shot rotate ~55us (demand pinned 2.6 TB/s). R7 lane-per-row
// float4: CRASH (84B pitch -> misaligned dwordx4). R8 64-row reg batches:
// SPILL (114MB scratch). R9 32-row depth-3 reg rotation: clean (no spill,
// VGPR=60) but 77us @ 1.9 TB/s -- conditional loads (`if lane<40/56/32`)
// make outstanding-load counts path-dependent, so SIInsertWaitcnts degrades
// to vmcnt(0) at every merge -> depth-3 collapsed to serial depth-1.
// R10: BRANCH-FREE wave body.
//  - full-wave unconditional loads: 3 o-float4 + 2 t-float4 per 32-row batch
//    (192/128 float4 incl ~5% overlap re-read; tail indices clamped with
//    branchless min -- buffer ends are exact page boundaries, overread faults).
//  - full-wave compute: row = lane&31, lanes l/l+32 duplicate (broadcast LDS
//    reads, free); finalize scales by 0.5.
//  - sched_barrier(0) at phase boundaries pins the depth-3 rotation so the
//    single-BB scheduler can't sink LDs into their WRs to save registers.
// -> statically exact counts: vmcnt(10) before each WR, 2 batches always in
// flight per wave (~9KB); 16 waves/CU -> ~150KB/CU in flight vs ~23KB needed.

#define NBLK 1024            // 1024 blk x 4 waves x 8 batches x 32 rows = B
#define INV_BN (1.0f / 3145728.0f)
#define OMAXI 5505023u       // out float4 count - 1 (1048576*84/16 - 1)
#define TMAXI 3932159u       // tgt float4 count - 1 (1048576*60/16 - 1)

__device__ __forceinline__ unsigned umin(unsigned a, unsigned b) {
  return a < b ? a : b;
}

// Per 32-row batch: o covers 168 float4 (load 192), t covers 120 (load 128).
#define LD(s, p)                                                   \
  {                                                                \
    const unsigned io = ob + (p) * 168u + (unsigned)lane;          \
    s##o0 = o4[io];                                                \
    s##o1 = o4[io + 64u];                                          \
    s##o2 = o4[umin(io + 128u, OMAXI)];                            \
    const unsigned it = tb + (p) * 120u + (unsigned)lane;          \
    s##t0 = t4[it];                                                \
    s##t1 = t4[umin(it + 64u, TMAXI)];                             \
  }

#define WR(s)                                                      \
  {                                                                \
    so4[lane] = s##o0;                                             \
    so4[lane + 64] = s##o1;                                        \
    so4[lane + 128] = s##o2;                                       \
    st4[lane] = s##t0;                                             \
    st4[lane + 64] = s##t1;                                        \
  }

#define PHASE(s, pnext)                                            \
  WR(s);                                                           \
  LD(s, pnext);                                                    \
  __builtin_amdgcn_sched_barrier(0);                               \
  acc += compute_row(so, st, lane & 31);

#define PHASE_END(s)                                               \
  WR(s);                                                           \
  __builtin_amdgcn_sched_barrier(0);                               \
  acc += compute_row(so, st, lane & 31);

// Row math from LDS. Stride 21/15 odd -> lanes 0..31 hit 32 distinct banks;
// lanes 32..63 duplicate lane&31 -> same-address broadcast (free).
__device__ __forceinline__ float compute_row(const float* so, const float* st,
                                             int row) {
  const float* o = so + row * 21;
  const float* t = st + row * 15;
  float pbce = 1.f, sx = 0.f, sy = 0.f, swh = 0.f, sel = 0.f;
  float Lg[3][3];
  int cls[3];
  #pragma unroll
  for (int n = 0; n < 3; ++n) {
    const float tt = t[n * 5 + 0];
    const bool mk = (tt != 0.f);
    const float m = mk ? 1.f : 0.f;
    const float p = o[n * 7 + 0];
    pbce *= mk ? p : 1.f - p;               // 3 logs -> 1
    const float dx = o[n * 7 + 1] * m - t[n * 5 + 1];
    sx += dx * dx;
    const float dy = o[n * 7 + 2] * m - t[n * 5 + 2];
    sy += dy * dy;
    const float o3 = o[n * 7 + 3], t3 = t[n * 5 + 3];
    swh += t3 + (mk ? (o3 - 2.f * __builtin_sqrtf(o3 * t3)) : 0.f);
    Lg[n][0] = o[n * 7 + 4] * m;
    Lg[n][1] = o[n * 7 + 5] * m;
    Lg[n][2] = o[n * 7 + 6] * m;
    cls[n] = (int)t[n * 5 + 4];
  }
  float prodS = 1.f;
  #pragma unroll
  for (int j = 0; j < 3; ++j) {
    prodS *= __expf(Lg[0][j]) + __expf(Lg[1][j]) + __expf(Lg[2][j]);
    const int idx = cls[j];
    sel += (idx == 0) ? Lg[0][j] : ((idx == 1) ? Lg[1][j] : Lg[2][j]);
  }
  return 5.f * (sx + sy + 2.f * swh) + 3.f * (__logf(prodS) - sel)
         - 0.5f * __logf(pbce);
}

__global__ __launch_bounds__(256, 4) void loc_loss_kernel(
    const float* __restrict__ gout, const float* __restrict__ gtgt,
    float* __restrict__ ws) {
  // Wave-private slot: 192 + 128 float4 = 5120 B; x4 waves = 20480 B/block.
  __shared__ alignas(16) float4 sO[4][192];
  __shared__ alignas(16) float4 sT[4][128];

  const int tid = threadIdx.x;
  const int w = tid >> 6;
  const int lane = tid & 63;
  const unsigned wg = blockIdx.x * 4u + (unsigned)w;  // 4096 waves, 256 rows
  const unsigned ob = wg * 1344u;   // float4 base of wave's out region
  const unsigned tb = wg * 960u;    // float4 base of wave's tgt region
  const float4* o4 = (const float4*)gout;
  const float4* t4 = (const float4*)gtgt;
  float4* so4 = sO[w];
  float4* st4 = sT[w];
  const float* so = (const float*)sO[w];
  const float* st = (const float*)sT[w];

  float4 Ao0, Ao1, Ao2, At0, At1;   // slot A: 20 VGPR
  float4 Bo0, Bo1, Bo2, Bt0, Bt1;   // slot B
  float4 Co0, Co1, Co2, Ct0, Ct1;   // slot C
  float acc = 0.f;

  LD(A, 0); LD(B, 1); LD(C, 2);
  __builtin_amdgcn_sched_barrier(0);
  PHASE(A, 3);      // batch 0; refill A with batch 3
  PHASE(B, 4);      // batch 1
  PHASE(C, 5);      // batch 2
  PHASE(A, 6);      // batch 3
  PHASE(B, 7);      // batch 4
  PHASE_END(C);     // batch 5
  PHASE_END(A);     // batch 6
  PHASE_END(B);     // batch 7

  // Lanes l and l+32 hold identical acc; partial = 2x wave row-sum.
  #pragma unroll
  for (int off = 32; off > 0; off >>= 1) acc += __shfl_down(acc, off, 64);
  if (lane == 0) ws[wg] = acc;
}

__global__ __launch_bounds__(256) void loc_loss_finalize(
    const float* __restrict__ ws, float* __restrict__ out) {
  __shared__ float s_wave[4];
  const int tid = threadIdx.x;
  const float4* w4 = (const float4*)ws;  // 4096 partials = 1024 float4
  float acc = 0.f;
  #pragma unroll
  for (int i = 0; i < 4; ++i) {
    float4 v = w4[tid + 256 * i];
    acc += (v.x + v.y) + (v.z + v.w);
  }
  #pragma unroll
  for (int off = 32; off > 0; off >>= 1) acc += __shfl_down(acc, off, 64);
  if ((tid & 63) == 0) s_wave[tid >> 6] = acc;
  __syncthreads();
  if (tid == 0) {
    // 0.5x undoes the duplicated-lane compute.
    out[0] = (s_wave[0] + s_wave[1] + s_wave[2] + s_wave[3])
             * (0.5f * INV_BN) + 0.5f;
  }
}

extern "C" void kernel_launch(void* const* d_in, const int* in_sizes, int n_in,
                              void* d_out, int out_size, void* d_ws, size_t ws_size,
                              hipStream_t stream) {
  const float* gout = (const float*)d_in[0];  // (B,3,7)
  const float* gtgt = (const float*)d_in[1];  // (B,3,5)
  float* ws = (float*)d_ws;                   // 4096 floats = 16 KB
  float* out = (float*)d_out;

  loc_loss_kernel<<<NBLK, 256, 0, stream>>>(gout, gtgt, ws);
  loc_loss_finalize<<<1, 256, 0, stream>>>(ws, out);
}

// Round 5
// 162.297 us; speedup vs baseline: 1.6701x; 1.6701x over previous
//
#include <hip/hip_runtime.h>

// LocalizationLoss: B=1048576, N=3, C=7. output (B,3,7) fp32, target (B,3,5) fp32.
// result = (5*(Sx+Sy+2*Swh) + 3*Sce - 0.5*Sbce)/(B*N) + 0.5   (scalar fp32)
//
// History: R3 barrier-dbuf 62us. R5 TLP-only 58us. R6 gl_lds 4-shot rotate
// ~55us (best; total 163.0). R7 misaligned-dwordx4 CRASH. R8 reg-stage 64row:
// spills. R9 depth-3 reg rotation: pipeline collapsed to depth-1 (77us).
// R10 sched_barrier(0)-pinned: spills again (197MB scratch, 159us).
// All gl_lds structures share ONE untested defect: compiler-visible ds_reads
// force s_waitcnt vmcnt(0) against ALL outstanding global_load_lds (no dest
// regs -> conservative ordering), so each shot's compute eats full latency
// INCLUDING the just-issued prefetch.
// R11 = R6 + counted waits (T4) via opaque reads:
//  - row reads are asm volatile ds_read2_b32/ds_read_b32 (compiler inserts no
//    vmcnt for them);
//  - manual s_waitcnt vmcnt(5) per shot (newest stage stays in flight; m135
//    oldest-first drain semantics), vmcnt(0) only for the final shot;
//  - rule #18: lgkmcnt(0) + sched_barrier(0) after the read cluster; memory
//    fences + sched_barrier(0) around waits and before refills so no gl_lds
//    crosses a count point;
//  - full-wave compute row=lane&31 (broadcast reads free), 0.5x in finalize;
//  - no min-waves launch bound -> no VGPR cap -> no spills.

#define NBLK 2048            // 2048 blocks x 4 waves x 4 shots x 32 rows = B
#define INV_BN (1.0f / 3145728.0f)

typedef float v2f __attribute__((ext_vector_type(2)));

__device__ __forceinline__ void gl16(const float4* g, float4* l) {
  // aux=2 -> NT (evict-first)
  __builtin_amdgcn_global_load_lds(
      (const __attribute__((address_space(1))) unsigned int*)g,
      (__attribute__((address_space(3))) unsigned int*)l, 16, 0, 2);
}

// Stage 32 rows: o = 32*21 = 168 float4; t = 32*15 = 120 float4. 5 gl_lds
// issued per call regardless of lane masks (wave-level vmcnt += 5).
__device__ __forceinline__ void stage32(const float* __restrict__ gout,
                                        const float* __restrict__ gtgt,
                                        size_t row0, int lane,
                                        float* so, float* st) {
  const float4* go4 = (const float4*)(gout + row0 * 21);
  const float4* gt4 = (const float4*)(gtgt + row0 * 15);
  float4* so4 = (float4*)so;
  float4* st4 = (float4*)st;
  gl16(go4 + lane, so4);
  gl16(go4 + 64 + lane, so4 + 64);
  if (lane < 40) gl16(go4 + 128 + lane, so4 + 128);
  gl16(gt4 + lane, st4);
  if (lane < 56) gl16(gt4 + 64 + lane, st4 + 64);
}

#define FENCE()                              \
  asm volatile("" ::: "memory");             \
  __builtin_amdgcn_sched_barrier(0)

#define WAITV(n)                                           \
  FENCE();                                                 \
  asm volatile("s_waitcnt vmcnt(" #n ")" ::: "memory");    \
  __builtin_amdgcn_sched_barrier(0)

#define DS2(dst, addr, a, b)                                          \
  asm volatile("ds_read2_b32 %0, %1 offset0:" #a " offset1:" #b       \
               : "=v"(dst) : "v"(addr))

// Opaque row read + math. oa/ta = LDS byte addresses of this lane's row.
__device__ __forceinline__ float row_math(unsigned oa, unsigned ta) {
  v2f oP0, oP1, oP2, oP3, oP4, oP5, oP6, oP7, oP8, oP9;
  float of20;
  v2f tP0, tP1, tP2, tP3, tP4, tP5, tP6;
  float tf14;
  DS2(oP0, oa, 0, 1);   DS2(oP1, oa, 2, 3);   DS2(oP2, oa, 4, 5);
  DS2(oP3, oa, 6, 7);   DS2(oP4, oa, 8, 9);   DS2(oP5, oa, 10, 11);
  DS2(oP6, oa, 12, 13); DS2(oP7, oa, 14, 15); DS2(oP8, oa, 16, 17);
  DS2(oP9, oa, 18, 19);
  asm volatile("ds_read_b32 %0, %1 offset:80" : "=v"(of20) : "v"(oa));
  DS2(tP0, ta, 0, 1);   DS2(tP1, ta, 2, 3);   DS2(tP2, ta, 4, 5);
  DS2(tP3, ta, 6, 7);   DS2(tP4, ta, 8, 9);   DS2(tP5, ta, 10, 11);
  DS2(tP6, ta, 12, 13);
  asm volatile("ds_read_b32 %0, %1 offset:56" : "=v"(tf14) : "v"(ta));
  asm volatile("s_waitcnt lgkmcnt(0)" ::: "memory");
  __builtin_amdgcn_sched_barrier(0);   // rule #18: no VALU hoists past the wait

  float pbce = 1.f, sx = 0.f, sy = 0.f, swh = 0.f, sel = 0.f;
  float Lg[3][3];
  // n = 0
  {
    const bool mk = (tP0.x != 0.f);
    const float m = mk ? 1.f : 0.f;
    pbce *= mk ? oP0.x : 1.f - oP0.x;
    const float dx = oP0.y * m - tP0.y; sx += dx * dx;
    const float dy = oP1.x * m - tP1.x; sy += dy * dy;
    const float o3 = oP1.y, t3 = tP1.y;
    swh += t3 + (mk ? (o3 - 2.f * __builtin_sqrtf(o3 * t3)) : 0.f);
    Lg[0][0] = oP2.x * m; Lg[0][1] = oP2.y * m; Lg[0][2] = oP3.x * m;
  }
  // n = 1
  {
    const bool mk = (tP2.y != 0.f);
    const float m = mk ? 1.f : 0.f;
    pbce *= mk ? oP3.y : 1.f - oP3.y;
    const float dx = oP4.x * m - tP3.x; sx += dx * dx;
    const float dy = oP4.y * m - tP3.y; sy += dy * dy;
    const float o3 = oP5.x, t3 = tP4.x;
    swh += t3 + (mk ? (o3 - 2.f * __builtin_sqrtf(o3 * t3)) : 0.f);
    Lg[1][0] = oP5.y * m; Lg[1][1] = oP6.x * m; Lg[1][2] = oP6.y * m;
  }
  // n = 2
  {
    const bool mk = (tP5.x != 0.f);
    const float m = mk ? 1.f : 0.f;
    pbce *= mk ? oP7.x : 1.f - oP7.x;
    const float dx = oP7.y * m - tP5.y; sx += dx * dx;
    const float dy = oP8.x * m - tP6.x; sy += dy * dy;
    const float o3 = oP8.y, t3 = tP6.y;
    swh += t3 + (mk ? (o3 - 2.f * __builtin_sqrtf(o3 * t3)) : 0.f);
    Lg[2][0] = oP9.x * m; Lg[2][1] = oP9.y * m; Lg[2][2] = of20 * m;
  }
  const int cls[3] = {(int)tP2.x, (int)tP4.y, (int)tf14};
  float prodS = 1.f;
  #pragma unroll
  for (int j = 0; j < 3; ++j) {
    prodS *= __expf(Lg[0][j]) + __expf(Lg[1][j]) + __expf(Lg[2][j]);
    const int idx = cls[j];
    sel += (idx == 0) ? Lg[0][j] : ((idx == 1) ? Lg[1][j] : Lg[2][j]);
  }
  return 5.f * (sx + sy + 2.f * swh) + 3.f * (__logf(prodS) - sel)
         - 0.5f * __logf(pbce);
}

__global__ __launch_bounds__(256) void loc_loss_kernel(
    const float* __restrict__ gout, const float* __restrict__ gtgt,
    float* __restrict__ ws) {
  // 2 rotating wave-private buffers x 4 waves: 36864 B -> 4 blocks/CU.
  __shared__ alignas(16) float sA_out[4][32 * 21];
  __shared__ alignas(16) float sA_tgt[4][32 * 15];
  __shared__ alignas(16) float sB_out[4][32 * 21];
  __shared__ alignas(16) float sB_tgt[4][32 * 15];

  const int tid = threadIdx.x;
  const int w = tid >> 6;
  const int lane = tid & 63;
  const int r = lane & 31;  // duplicated rows on upper half-wave (broadcast)
  const size_t base = ((size_t)blockIdx.x * 4 + w) * 128;  // 4 shots x 32 rows

  // LDS byte addresses of this lane's row in each buffer (AS3 offset).
  const unsigned oA = (unsigned)(uintptr_t)(
      (__attribute__((address_space(3))) float*)&sA_out[w][0]) + r * 84u;
  const unsigned tA = (unsigned)(uintptr_t)(
      (__attribute__((address_space(3))) float*)&sA_tgt[w][0]) + r * 60u;
  const unsigned oB = (unsigned)(uintptr_t)(
      (__attribute__((address_space(3))) float*)&sB_out[w][0]) + r * 84u;
  const unsigned tB = (unsigned)(uintptr_t)(
      (__attribute__((address_space(3))) float*)&sB_tgt[w][0]) + r * 60u;

  float acc = 0.f;
  // Stages: s0->A, s1->B | wait(5): s0 done, s1 flying | read A, refill s2->A
  // | wait(5): s1 done, s2 flying | read B, refill s3->B | wait(5): s2 done
  // | read A | wait(0): s3 done | read B.
  stage32(gout, gtgt, base +  0, lane, sA_out[w], sA_tgt[w]);
  stage32(gout, gtgt, base + 32, lane, sB_out[w], sB_tgt[w]);
  WAITV(5);
  acc += row_math(oA, tA);
  FENCE();
  stage32(gout, gtgt, base + 64, lane, sA_out[w], sA_tgt[w]);
  WAITV(5);
  acc += row_math(oB, tB);
  FENCE();
  stage32(gout, gtgt, base + 96, lane, sB_out[w], sB_tgt[w]);
  WAITV(5);
  acc += row_math(oA, tA);
  WAITV(0);
  acc += row_math(oB, tB);

  // Lanes l and l+32 hold identical acc -> partial is 2x; finalize scales 0.5.
  #pragma unroll
  for (int off = 32; off > 0; off >>= 1) acc += __shfl_down(acc, off, 64);
  if (lane == 0) ws[(size_t)blockIdx.x * 4 + w] = acc;
}

__global__ __launch_bounds__(256) void loc_loss_finalize(
    const float* __restrict__ ws, float* __restrict__ out) {
  __shared__ float s_wave[4];
  const int tid = threadIdx.x;
  const float4* w4 = (const float4*)ws;  // 8192 partials = 2048 float4
  float acc = 0.f;
  #pragma unroll
  for (int i = 0; i < 8; ++i) {
    float4 v = w4[tid + 256 * i];
    acc += (v.x + v.y) + (v.z + v.w);
  }
  #pragma unroll
  for (int off = 32; off > 0; off >>= 1) acc += __shfl_down(acc, off, 64);
  if ((tid & 63) == 0) s_wave[tid >> 6] = acc;
  __syncthreads();
  if (tid == 0) {
    // 0.5x undoes duplicated-lane compute.
    out[0] = (s_wave[0] + s_wave[1] + s_wave[2] + s_wave[3])
             * (0.5f * INV_BN) + 0.5f;
  }
}

extern "C" void kernel_launch(void* const* d_in, const int* in_sizes, int n_in,
                              void* d_out, int out_size, void* d_ws, size_t ws_size,
                              hipStream_t stream) {
  const float* gout = (const float*)d_in[0];  // (B,3,7)
  const float* gtgt = (const float*)d_in[1];  // (B,3,5)
  float* ws = (float*)d_ws;                   // 8192 floats = 32 KB
  float* out = (float*)d_out;

  loc_loss_kernel<<<NBLK, 256, 0, stream>>>(gout, gtgt, ws);
  loc_loss_finalize<<<1, 256, 0, stream>>>(ws, out);
}